// Round 14
// baseline (108.218 us; speedup 1.0000x reference)
//
#include <hip/hip_runtime.h>
#include <hip/hip_bf16.h>
#include <math.h>

static constexpr int Bc = 2, Hc = 16, Tc = 2048, DKc = 64, DMc = 1024, NQKV = 3072;
// exp2-units scale folded into Q: log2(e)/sqrt(64)
#define QSCALE 0.18033688011112042f

typedef unsigned short u16;
typedef unsigned int u32;
typedef short s8v __attribute__((ext_vector_type(8)));
typedef float f32x4 __attribute__((ext_vector_type(4)));
typedef float f32x16 __attribute__((ext_vector_type(16)));
typedef int i32x4 __attribute__((ext_vector_type(4)));

#define DEVINL __device__ __forceinline__

DEVINL u16 f2b(float f) {
    union { float f; unsigned u; } v; v.f = f;
    unsigned u = v.u;
    unsigned r = (u + 0x7fffu + ((u >> 16) & 1u)) >> 16; // RNE
    return (u16)r;
}

DEVINL u32 pkbf16(float lo, float up) {
    u32 r;
    asm volatile("v_cvt_pk_bf16_f32 %0, %1, %2" : "=v"(r) : "v"(lo), "v"(up));
    return r;
}

// raw v_exp_f32 (2^x). S is bounded (~|x|<12) -> no denorm/range fixup needed.
DEVINL float vexp2(float x) {
    float r;
    asm("v_exp_f32 %0, %1" : "=v"(r) : "v"(x));
    return r;
}

// a' = {a[0:31], b[0:31] pulled to hi}; b' = {a[32:63] pulled to lo, b[32:63]}
DEVINL void pl32swap(u32& a, u32& b) {
    asm volatile("v_permlane32_swap_b32 %0, %1" : "+v"(a), "+v"(b));
}

DEVINL void gl_lds(const void* g, void* l) {
    __builtin_amdgcn_global_load_lds(
        (const __attribute__((address_space(1))) unsigned int*)g,
        (__attribute__((address_space(3))) unsigned int*)l, 16, 0, 0);
}

DEVINL s8v as_s8v(i32x4 x) { union { i32x4 i; s8v v; } u; u.i = x; return u.v; }

// ---------------------------------------------------------------------------
// Fused prepass: bid<1024 -> X fp32->bf16; else 64x64 transpose-convert tiles
// of Wqkv (768 blocks) or Wout (256 blocks).
// ---------------------------------------------------------------------------
DEVINL void transw_tile(const float* __restrict__ W, u16* __restrict__ Wt,
                        int N, int K, int n0, int k0, u16 (*LT)[72], int t) {
    const int rr = t >> 4, cc = (t & 15) * 4;
    #pragma unroll
    for (int it = 0; it < 4; it++) {
        const int row = it * 16 + rr;  // k-local
        float4 f = *(const float4*)&W[(size_t)(k0 + row) * N + n0 + cc];
        union { u16 u[4]; uint2 d; } o;
        o.u[0] = f2b(f.x); o.u[1] = f2b(f.y); o.u[2] = f2b(f.z); o.u[3] = f2b(f.w);
        *(uint2*)&LT[row][cc] = o.d;
    }
    __syncthreads();
    #pragma unroll
    for (int it = 0; it < 4; it++) {
        const int nrow = it * 16 + rr;
        union { u16 u[4]; uint2 d; } o;
        #pragma unroll
        for (int j = 0; j < 4; j++) o.u[j] = LT[cc + j][nrow];
        *(uint2*)&Wt[(size_t)(n0 + nrow) * K + k0 + cc] = o.d;
    }
}

__global__ __launch_bounds__(256) void prepass(
    const float* __restrict__ X, u16* __restrict__ Xb,
    const float* __restrict__ Wqkv, u16* __restrict__ Wt1,
    const float* __restrict__ Wout, u16* __restrict__ Wt2)
{
    __shared__ u16 LT[64][72];
    const int bid = blockIdx.x, t = threadIdx.x;
    if (bid < 1024) {
        const int n4 = (Bc * Tc * DMc) / 4;
        for (int i = bid * 256 + t; i < n4; i += 1024 * 256) {
            float4 f = ((const float4*)X)[i];
            union { u16 u[4]; uint2 d; } o;
            o.u[0] = f2b(f.x); o.u[1] = f2b(f.y); o.u[2] = f2b(f.z); o.u[3] = f2b(f.w);
            ((uint2*)Xb)[i] = o.d;
        }
    } else if (bid < 1024 + 768) {
        const int b2 = bid - 1024;   // Wqkv: N=3072 (48 tiles), K=1024 (16)
        transw_tile(Wqkv, Wt1, NQKV, DMc, (b2 % 48) * 64, (b2 / 48) * 64, LT, t);
    } else {
        const int b2 = bid - 1792;   // Wout: N=1024 (16 tiles), K=1024 (16)
        transw_tile(Wout, Wt2, DMc, DMc, (b2 % 16) * 64, (b2 / 16) * 64, LT, t);
    }
}

// ---------------------------------------------------------------------------
// GEMM-KP: k-parity split at CONSTANT occupancy (minimal delta from gemm_cv).
// 128x128 block, 8 waves = 2 parity groups x (2x2 grid of 64x64 wave tiles).
// Same 32KB dbuf LDS + counted-vmcnt loop as gemm_cv (3 blocks/CU). All waves
// stage every tile; iter t computed only by group t&1 (its tiles are always
// in slot g). Per block-iter: 64 MFMA (unchanged), LDS frag reads 48->32KB.
// Epilogue: 2-round merge via freed tile LDS (8KB/wave-pair, chunk-contig,
// conflict-free), then group0 writes C.
// ---------------------------------------------------------------------------
template <int EPI>
__global__ __launch_bounds__(512) void gemm_kp(
    const u16* __restrict__ A, const u16* __restrict__ Bt,
    const float* __restrict__ bias,
    u16* __restrict__ q_out, u16* __restrict__ k_out, u16* __restrict__ v_out,
    float* __restrict__ f_out, int M, int N, int K, int ntn)
{
    __shared__ __align__(16) char Lds[32768];  // A slots: [0,16K); B slots: [16K,32K)
    const int tid = threadIdx.x, lane = tid & 63, w = tid >> 6;
    const int qd = gridDim.x >> 3;   // grid % 8 == 0
    const int wg = (blockIdx.x & 7) * qd + (blockIdx.x >> 3);
    const int m0 = (wg / ntn) * 128, n0 = (wg % ntn) * 128;
    const int g = w >> 2, sub = w & 3;
    const int wgm = sub >> 1, wgn = sub & 1;   // 64x64 wave tile position

    f32x4 acc[4][4] = {};
    const int nt = K >> 5;

    const int srow = tid >> 2;                          // staged row 0..127
    const int skc  = ((tid & 3) ^ ((srow >> 1) & 3)) * 8;  // pre-swizzled src k

#define STG(t_) do {                                                           \
        const int s_ = (t_) & 1;                                               \
        gl_lds(A + (size_t)(m0 + srow) * K + ((t_) << 5) + skc,                \
               Lds + s_ * 8192 + w * 1024);                                    \
        gl_lds(Bt + (size_t)(n0 + srow) * K + ((t_) << 5) + skc,               \
               Lds + 16384 + s_ * 8192 + w * 1024);                            \
    } while (0)
#define BARX() do { __builtin_amdgcn_sched_barrier(0);                         \
        __builtin_amdgcn_s_barrier();                                          \
        __builtin_amdgcn_sched_barrier(0); } while (0)

    STG(0);
    for (int t = 0; t < nt; t++) {
        if (t + 1 < nt) {
            STG(t + 1);
            asm volatile("s_waitcnt vmcnt(2)" ::: "memory");   // drain tile t only
        } else {
            asm volatile("s_waitcnt vmcnt(0)" ::: "memory");
        }
        BARX();                      // tile t staged for all waves
        if ((t & 1) == g) {          // my parity: compute from slot g
            const char* Ab = Lds + g * 8192;
            const char* Bb = Lds + 16384 + g * 8192;
            s8v af[4], bf[4];
            #pragma unroll
            for (int mi = 0; mi < 4; mi++) {
                const int row = wgm * 64 + mi * 16 + (lane & 15);
                const int s16 = (lane >> 4) ^ ((row >> 1) & 3);
                af[mi] = *(const s8v*)(Ab + row * 64 + s16 * 16);
            }
            #pragma unroll
            for (int ni = 0; ni < 4; ni++) {
                const int row = wgn * 64 + ni * 16 + (lane & 15);
                const int s16 = (lane >> 4) ^ ((row >> 1) & 3);
                bf[ni] = *(const s8v*)(Bb + row * 64 + s16 * 16);
            }
            __builtin_amdgcn_s_setprio(1);
            #pragma unroll
            for (int mi = 0; mi < 4; mi++)
                #pragma unroll
                for (int ni = 0; ni < 4; ni++)
                    acc[mi][ni] = __builtin_amdgcn_mfma_f32_16x16x32_bf16(
                        af[mi], bf[ni], acc[mi][ni], 0, 0, 0);
            __builtin_amdgcn_s_setprio(0);
        }
        BARX();                      // all reads of this slot retired
    }
#undef STG
#undef BARX

    // k-parity merge: 2 rounds of 8 chunks (8KB/wave-pair, chunk-contiguous).
    #pragma unroll
    for (int half = 0; half < 2; half++) {
        if (g == 1) {
            char* dst = Lds + sub * 8192;
            #pragma unroll
            for (int mi = 0; mi < 2; mi++)
                #pragma unroll
                for (int ni = 0; ni < 4; ni++)
                    *(f32x4*)(dst + (mi * 4 + ni) * 1024 + lane * 16) = acc[half * 2 + mi][ni];
        }
        __syncthreads();
        if (g == 0) {
            const char* src = Lds + sub * 8192;
            #pragma unroll
            for (int mi = 0; mi < 2; mi++)
                #pragma unroll
                for (int ni = 0; ni < 4; ni++)
                    acc[half * 2 + mi][ni] += *(const f32x4*)(src + (mi * 4 + ni) * 1024 + lane * 16);
        }
        __syncthreads();
    }

    if (g == 0) {
        #pragma unroll
        for (int mi = 0; mi < 4; mi++)
        #pragma unroll
        for (int ni = 0; ni < 4; ni++)
        #pragma unroll
        for (int r = 0; r < 4; r++) {
            const int row = m0 + wgm * 64 + mi * 16 + (lane >> 4) * 4 + r;
            const int col = n0 + wgn * 64 + ni * 16 + (lane & 15);
            const float val = acc[mi][ni][r] + bias[col];
            if constexpr (EPI == 0) {
                const int sel = col >> 10, rem = col & 1023;
                const int h = rem >> 6, d = rem & 63;
                const int b = row >> 11, tt = row & 2047;
                const size_t idx = ((size_t)(b * Hc + h) * Tc + tt) * DKc + d;
                if (sel == 0) q_out[idx] = f2b(val * QSCALE);
                else if (sel == 1) k_out[idx] = f2b(val);
                else v_out[idx] = f2b(val);
            } else {
                f_out[(size_t)row * N + col] = val;
            }
        }
    }
}

// ---------------------------------------------------------------------------
// GEMM-CV (proven r12): 128x128, 8 waves of 64x32, 32KB dbuf, counted vmcnt.
// Used for GEMM2.
// ---------------------------------------------------------------------------
template <int EPI>
__global__ __launch_bounds__(512) void gemm_cv(
    const u16* __restrict__ A, const u16* __restrict__ Bt,
    const float* __restrict__ bias,
    u16* __restrict__ q_out, u16* __restrict__ k_out, u16* __restrict__ v_out,
    float* __restrict__ f_out, int M, int N, int K, int ntn)
{
    __shared__ __align__(16) u16 Al[2][128 * 32];
    __shared__ __align__(16) u16 Bl[2][128 * 32];
    const int tid = threadIdx.x, lane = tid & 63, w = tid >> 6;
    const int qd = gridDim.x >> 3;
    const int wg = (blockIdx.x & 7) * qd + (blockIdx.x >> 3);
    const int m0 = (wg / ntn) * 128, n0 = (wg % ntn) * 128;
    const int wm = w >> 2, wn = w & 3;

    f32x4 acc[4][2] = {};
    const int nt = K >> 5;

    const int srow = tid >> 2;
    const int skc  = ((tid & 3) ^ ((srow >> 1) & 3)) * 8;

#define STG(t_, s_) do {                                                       \
        const int kk_ = (t_) << 5;                                             \
        gl_lds(A + (size_t)(m0 + srow) * K + kk_ + skc,                        \
               (char*)&Al[s_][0] + w * 1024);                                  \
        gl_lds(Bt + (size_t)(n0 + srow) * K + kk_ + skc,                       \
               (char*)&Bl[s_][0] + w * 1024);                                  \
    } while (0)
#define BARX() do { __builtin_amdgcn_sched_barrier(0);                         \
        __builtin_amdgcn_s_barrier();                                          \
        __builtin_amdgcn_sched_barrier(0); } while (0)

    STG(0, 0);
    int buf = 0;
    for (int t = 0; t < nt; t++) {
        if (t + 1 < nt) {
            STG(t + 1, buf ^ 1);
            asm volatile("s_waitcnt vmcnt(2)" ::: "memory");
        } else {
            asm volatile("s_waitcnt vmcnt(0)" ::: "memory");
        }
        BARX();
        s8v af[4], bf[2];
        #pragma unroll
        for (int mi = 0; mi < 4; mi++) {
            const int row = wm * 64 + mi * 16 + (lane & 15);
            const int slot = (lane >> 4) ^ ((row >> 1) & 3);
            af[mi] = *(const s8v*)((const char*)&Al[buf][0] + row * 64 + slot * 16);
        }
        #pragma unroll
        for (int ni = 0; ni < 2; ni++) {
            const int row = wn * 32 + ni * 16 + (lane & 15);
            const int slot = (lane >> 4) ^ ((row >> 1) & 3);
            bf[ni] = *(const s8v*)((const char*)&Bl[buf][0] + row * 64 + slot * 16);
        }
        #pragma unroll
        for (int mi = 0; mi < 4; mi++)
            #pragma unroll
            for (int ni = 0; ni < 2; ni++)
                acc[mi][ni] = __builtin_amdgcn_mfma_f32_16x16x32_bf16(af[mi], bf[ni], acc[mi][ni], 0, 0, 0);
        BARX();
        buf ^= 1;
    }
#undef STG
#undef BARX

    #pragma unroll
    for (int mi = 0; mi < 4; mi++)
    #pragma unroll
    for (int ni = 0; ni < 2; ni++)
    #pragma unroll
    for (int r = 0; r < 4; r++) {
        const int row = m0 + wm * 64 + mi * 16 + (lane >> 4) * 4 + r;
        const int col = n0 + wn * 32 + ni * 16 + (lane & 15);
        const float val = acc[mi][ni][r] + bias[col];
        if constexpr (EPI == 0) {
            const int sel = col >> 10, rem = col & 1023;
            const int h = rem >> 6, d = rem & 63;
            const int b = row >> 11, tt = row & 2047;
            const size_t idx = ((size_t)(b * Hc + h) * Tc + tt) * DKc + d;
            if (sel == 0) q_out[idx] = f2b(val * QSCALE);
            else if (sel == 1) k_out[idx] = f2b(val);
            else v_out[idx] = f2b(val);
        } else {
            f_out[(size_t)row * N + col] = val;
        }
    }
}

// ---------------------------------------------------------------------------
// Flash attention, causal, swapped-QK^T 32x32, m=0 linear accumulation.
// 512 threads = 2 wave-groups x 4 waves; group g owns k-half [g*h, g*h+h).
// ---------------------------------------------------------------------------
__global__ __launch_bounds__(512) void attn_fwd(
    const u16* __restrict__ Q, const u16* __restrict__ K,
    const u16* __restrict__ V, u16* __restrict__ O)
{
    __shared__ __align__(16) char Gl[2][2][2][8192];

    const int bid = blockIdx.x;
    const int bh = bid & 31;
    const int qt = 15 - (bid >> 5);
    const int tid = threadIdx.x;
    const int g = tid >> 8;
    const int gtid = tid & 255;
    const int lane = tid & 63;
    const int ws = (tid >> 6) & 3;
    const int hi = lane >> 5, lq = lane & 31;
    const int q0w = qt * 128 + ws * 32;
    const int qg = q0w + lq;

    const u16* Qb = Q + (size_t)bh * (Tc * DKc);
    const u16* Kb = K + (size_t)bh * (Tc * DKc);
    const u16* Vb = V + (size_t)bh * (Tc * DKc);

    s8v qf[4];
    #pragma unroll
    for (int st = 0; st < 4; st++)
        qf[st] = *(const s8v*)(Qb + (size_t)qg * 64 + st * 16 + hi * 8);

    f32x16 o0 = {}, o1 = {}, lacc = {};

    const int dtw = (q0w + 31) >> 6;
    const int h = qt + 1;
    const int t0 = g * h;

    char* const Kbase = &Gl[g][0][0][0];
    char* const Vbase = &Gl[g][1][0][0];

    const int d2 = (gtid & 31) * 2, kb8 = gtid >> 5;
    const unsigned vsw0 = ((unsigned)(d2 & 7)) << 4;
    const unsigned vsw1 = ((unsigned)((d2 + 1) & 7)) << 4;
    const unsigned ksw = ((unsigned)(lq & 7)) << 4;

    u32 vx[8];

#define ISSUE_K(kt_, dst_) do {                                              \
        const char* Ktile_ = (const char*)(Kb + (size_t)(kt_) * 4096);       \
        _Pragma("unroll")                                                    \
        for (int s_ = 0; s_ < 2; s_++) {                                     \
            const int o_ = s_ * 4096 + gtid * 16;                            \
            const int rk_ = o_ >> 7;                                         \
            const int cb_ = (o_ & 127) ^ ((rk_ & 7) << 4);                   \
            gl_lds(Ktile_ + rk_ * 128 + cb_, (dst_) + s_ * 4096 + ws * 1024); \
        }                                                                    \
    } while (0)

#define LOAD_V(kt_) do {                                                     \
        const u16* Vtile_ = Vb + (size_t)(kt_) * 4096;                       \
        _Pragma("unroll")                                                    \
        for (int i_ = 0; i_ < 8; i_++)                                       \
            vx[i_] = *(const u32*)(Vtile_ + (kb8 * 8 + i_) * 64 + d2);       \
    } while (0)

#define WRITE_V(dst_) do {                                                   \
        s8v v0_, v1_;                                                        \
        _Pragma("unroll")                                                    \
        for (int i_ = 0; i_ < 8; i_++) {                                     \
            v0_[i_] = (short)(vx[i_] & 0xffff);                              \
            v1_[i_] = (short)(vx[i_] >> 16);                                 \
        }                                                                    \
        *(s8v*)((dst_) + d2 * 128 + (((unsigned)(kb8 * 16)) ^ vsw0)) = v0_;  \
        *(s8v*)((dst_) + (d2 + 1) * 128 + (((unsigned)(kb8 * 16)) ^ vsw1)) = v1_; \
    } while (0)

    ISSUE_K(t0, Kbase);
    LOAD_V(t0);
    WRITE_V(Vbase);
    __syncthreads();

    int c = 0;
    for (int i = 0; i < h; i++) {
        const int tki = t0 + i;
        const bool pf_next = (i + 1 < h);
        if (pf_next) {
            ISSUE_K(tki + 1, Kbase + (c ^ 1) * 8192);
            LOAD_V(tki + 1);
        }

        if (tki <= dtw) {
            const char* Kc = Kbase + c * 8192;
            const char* Vc = Vbase + c * 8192;
            f32x16 s0v = {}, s1v = {};
            __builtin_amdgcn_s_setprio(1);
            #pragma unroll
            for (int st = 0; st < 4; st++) {
                const unsigned cbs = (unsigned)(st * 32 + hi * 16);
                s8v kf0 = *(const s8v*)(Kc + lq * 128 + (cbs ^ ksw));
                s8v kf1 = *(const s8v*)(Kc + (32 + lq) * 128 + (cbs ^ ksw));
                s0v = __builtin_amdgcn_mfma_f32_32x32x16_bf16(kf0, qf[st], s0v, 0, 0, 0);
                s1v = __builtin_amdgcn_mfma_f32_32x32x16_bf16(kf1, qf[st], s1v, 0, 0, 0);
            }
            __builtin_amdgcn_s_setprio(0);

            if (tki == dtw) {
                #pragma unroll
                for (int r = 0; r < 16; r++) {
                    const int kg = tki * 64 + (r & 3) + 8 * (r >> 2) + 4 * hi;
                    if (kg > qg) s0v[r] = -INFINITY;
                    if (kg + 32 > qg) s1v[r] = -INFINITY;
                }
            }

            #pragma unroll
            for (int r = 0; r < 16; r++) {
                s0v[r] = vexp2(s0v[r]);
                s1v[r] = vexp2(s1v[r]);
            }
            lacc += s0v;
            lacc += s1v;

            i32x4 pf[4];
            #pragma unroll
            for (int gq = 0; gq < 2; gq++) {
                #pragma unroll
                for (int hq = 0; hq < 2; hq++) {
                    const int base = hq * 8;
                    u32 a0, a1, b0, b1;
                    if (gq == 0) {
                        a0 = pkbf16(s0v[base + 0], s0v[base + 1]);
                        a1 = pkbf16(s0v[base + 2], s0v[base + 3]);
                        b0 = pkbf16(s0v[base + 4], s0v[base + 5]);
                        b1 = pkbf16(s0v[base + 6], s0v[base + 7]);
                    } else {
                        a0 = pkbf16(s1v[base + 0], s1v[base + 1]);
                        a1 = pkbf16(s1v[base + 2], s1v[base + 3]);
                        b0 = pkbf16(s1v[base + 4], s1v[base + 5]);
                        b1 = pkbf16(s1v[base + 6], s1v[base + 7]);
                    }
                    pl32swap(a0, b0);
                    pl32swap(a1, b1);
                    pf[gq * 2 + hq][0] = (int)a0;
                    pf[gq * 2 + hq][1] = (int)a1;
                    pf[gq * 2 + hq][2] = (int)b0;
                    pf[gq * 2 + hq][3] = (int)b1;
                }
            }

            __builtin_amdgcn_s_setprio(1);
            #pragma unroll
            for (int ks = 0; ks < 4; ks++) {
                const unsigned cbv = (unsigned)(ks * 32 + hi * 16);
                s8v vf0 = *(const s8v*)(Vc + lq * 128 + (cbv ^ ksw));
                s8v vf1 = *(const s8v*)(Vc + (32 + lq) * 128 + (cbv ^ ksw));
                const s8v pa = as_s8v(pf[ks]);
                o0 = __builtin_amdgcn_mfma_f32_32x32x16_bf16(pa, vf0, o0, 0, 0, 0);
                o1 = __builtin_amdgcn_mfma_f32_32x32x16_bf16(pa, vf1, o1, 0, 0, 0);
            }
            __builtin_amdgcn_s_setprio(0);
        }

        if (pf_next) WRITE_V(Vbase + (c ^ 1) * 8192);
        __syncthreads();
        c ^= 1;
    }

    float t8[8];
    #pragma unroll
    for (int r = 0; r < 8; r++) t8[r] = lacc[r] + lacc[r + 8];
    #pragma unroll
    for (int off = 4; off >= 1; off >>= 1)
        #pragma unroll
        for (int r = 0; r < off; r++) t8[r] = t8[r] + t8[r + off];
    float ls = t8[0] + __shfl_xor(t8[0], 32);

    float* Pf = (float*)(&Gl[0][0][0][0]) + ws * 2304;
    if (g == 1) {
        float* dst = Pf + lane * 34;
        #pragma unroll
        for (int r = 0; r < 16; r++) { dst[r] = o0[r]; dst[16 + r] = o1[r]; }
        Pf[2176 + lane] = ls;
    }
    __syncthreads();
    if (g == 0) {
        const float* src = Pf + lane * 34;
        #pragma unroll
        for (int r = 0; r < 16; r++) { o0[r] += src[r]; o1[r] += src[16 + r]; }
        ls += Pf[2176 + lane];

        const float linv = 1.0f / ls;
        const int b = bh >> 4, hh = bh & 15;
        u16* Ob = O + ((size_t)b * Tc) * DMc + hh * 64;
        #pragma unroll
        for (int r = 0; r < 16; r++) {
            const int cr = (r & 3) + 8 * (r >> 2) + 4 * hi;
            const float ir = __shfl(linv, cr);
            u16* orow = Ob + (size_t)(q0w + cr) * DMc;
            orow[lq]      = f2b(o0[r] * ir);
            orow[32 + lq] = f2b(o1[r] * ir);
        }
    }
#undef ISSUE_K
#undef LOAD_V
#undef WRITE_V
}

// ---------------------------------------------------------------------------
extern "C" void kernel_launch(void* const* d_in, const int* in_sizes, int n_in,
                              void* d_out, int out_size, void* d_ws, size_t ws_size,
                              hipStream_t stream)
{
    const float* X    = (const float*)d_in[0];
    const float* Wqkv = (const float*)d_in[1];
    const float* bqkv = (const float*)d_in[2];
    const float* Wout = (const float*)d_in[3];
    const float* bout = (const float*)d_in[4];
    float* out = (float*)d_out;

    char* ws = (char*)d_ws;
    u16* Xb  = (u16*)(ws);                      // 8 MB (dead after GEMM1)
    u16* Ow  = (u16*)(ws);                      // 8 MB (overlays Xb)
    u16* Wt1 = (u16*)(ws + (8 << 20));          // 6 MB
    u16* Wt2 = (u16*)(ws + (14 << 20));         // 2 MB
    u16* Qw  = (u16*)(ws + (16 << 20));         // 8 MB
    u16* Kw  = (u16*)(ws + (24 << 20));         // 8 MB
    u16* Vw  = (u16*)(ws + (32 << 20));         // 8 MB

    // fused prepass: conv(1024) + transw Wqkv(768) + transw Wout(256)
    prepass<<<2048, 256, 0, stream>>>(X, Xb, Wqkv, Wt1, Wout, Wt2);

    // GEMM1: 128x128 k-parity (64x64 wave tiles, 32KB LDS), grid 768 (3/CU)
    gemm_kp<0><<<768, 512, 0, stream>>>(
        Xb, Wt1, bqkv, Qw, Kw, Vw, nullptr, Bc * Tc, NQKV, DMc, NQKV / 128);

    attn_fwd<<<512, 512, 0, stream>>>(Qw, Kw, Vw, Ow);

    // GEMM2: proven gemm_cv, grid 256
    gemm_cv<1><<<256, 512, 0, stream>>>(
        Ow, Wt2, bout, nullptr, nullptr, nullptr, out, Bc * Tc, DMc, DMc, DMc / 128);
}

// Round 15
// 97.190 us; speedup vs baseline: 1.1135x; 1.1135x over previous
//
#include <hip/hip_runtime.h>
#include <hip/hip_bf16.h>
#include <math.h>

static constexpr int Bc = 2, Hc = 16, Tc = 2048, DKc = 64, DMc = 1024, NQKV = 3072;
// exp2-units scale folded into Q: log2(e)/sqrt(64)
#define QSCALE 0.18033688011112042f

typedef unsigned short u16;
typedef unsigned int u32;
typedef short s8v __attribute__((ext_vector_type(8)));
typedef float f32x4 __attribute__((ext_vector_type(4)));
typedef float f32x16 __attribute__((ext_vector_type(16)));
typedef int i32x4 __attribute__((ext_vector_type(4)));

#define DEVINL __device__ __forceinline__

DEVINL u16 f2b(float f) {
    union { float f; unsigned u; } v; v.f = f;
    unsigned u = v.u;
    unsigned r = (u + 0x7fffu + ((u >> 16) & 1u)) >> 16; // RNE
    return (u16)r;
}

DEVINL u32 pkbf16(float lo, float up) {
    u32 r;
    asm volatile("v_cvt_pk_bf16_f32 %0, %1, %2" : "=v"(r) : "v"(lo), "v"(up));
    return r;
}

// raw v_exp_f32 (2^x). S is bounded (~|x|<12) -> no denorm/range fixup needed.
DEVINL float vexp2(float x) {
    float r;
    asm("v_exp_f32 %0, %1" : "=v"(r) : "v"(x));
    return r;
}

// a' = {a[0:31], b[0:31] pulled to hi}; b' = {a[32:63] pulled to lo, b[32:63]}
DEVINL void pl32swap(u32& a, u32& b) {
    asm volatile("v_permlane32_swap_b32 %0, %1" : "+v"(a), "+v"(b));
}

DEVINL void gl_lds(const void* g, void* l) {
    __builtin_amdgcn_global_load_lds(
        (const __attribute__((address_space(1))) unsigned int*)g,
        (__attribute__((address_space(3))) unsigned int*)l, 16, 0, 0);
}

DEVINL s8v as_s8v(i32x4 x) { union { i32x4 i; s8v v; } u; u.i = x; return u.v; }

// ---------------------------------------------------------------------------
// Fused prepass: bid<1024 -> X fp32->bf16; else 64x64 transpose-convert tiles
// of Wqkv (768 blocks) or Wout (256 blocks).
// ---------------------------------------------------------------------------
DEVINL void transw_tile(const float* __restrict__ W, u16* __restrict__ Wt,
                        int N, int K, int n0, int k0, u16 (*LT)[72], int t) {
    const int rr = t >> 4, cc = (t & 15) * 4;
    #pragma unroll
    for (int it = 0; it < 4; it++) {
        const int row = it * 16 + rr;  // k-local
        float4 f = *(const float4*)&W[(size_t)(k0 + row) * N + n0 + cc];
        union { u16 u[4]; uint2 d; } o;
        o.u[0] = f2b(f.x); o.u[1] = f2b(f.y); o.u[2] = f2b(f.z); o.u[3] = f2b(f.w);
        *(uint2*)&LT[row][cc] = o.d;
    }
    __syncthreads();
    #pragma unroll
    for (int it = 0; it < 4; it++) {
        const int nrow = it * 16 + rr;
        union { u16 u[4]; uint2 d; } o;
        #pragma unroll
        for (int j = 0; j < 4; j++) o.u[j] = LT[cc + j][nrow];
        *(uint2*)&Wt[(size_t)(n0 + nrow) * K + k0 + cc] = o.d;
    }
}

__global__ __launch_bounds__(256) void prepass(
    const float* __restrict__ X, u16* __restrict__ Xb,
    const float* __restrict__ Wqkv, u16* __restrict__ Wt1,
    const float* __restrict__ Wout, u16* __restrict__ Wt2)
{
    __shared__ u16 LT[64][72];
    const int bid = blockIdx.x, t = threadIdx.x;
    if (bid < 1024) {
        const int n4 = (Bc * Tc * DMc) / 4;
        for (int i = bid * 256 + t; i < n4; i += 1024 * 256) {
            float4 f = ((const float4*)X)[i];
            union { u16 u[4]; uint2 d; } o;
            o.u[0] = f2b(f.x); o.u[1] = f2b(f.y); o.u[2] = f2b(f.z); o.u[3] = f2b(f.w);
            ((uint2*)Xb)[i] = o.d;
        }
    } else if (bid < 1024 + 768) {
        const int b2 = bid - 1024;   // Wqkv: N=3072 (48 tiles), K=1024 (16)
        transw_tile(Wqkv, Wt1, NQKV, DMc, (b2 % 48) * 64, (b2 / 48) * 64, LT, t);
    } else {
        const int b2 = bid - 1792;   // Wout: N=1024 (16 tiles), K=1024 (16)
        transw_tile(Wout, Wt2, DMc, DMc, (b2 % 16) * 64, (b2 / 16) * 64, LT, t);
    }
}

// ---------------------------------------------------------------------------
// GEMM-CV (champion, r10/r12): 128x128, 8 waves of 64x32, 32KB dbuf LDS,
// counted-vmcnt loop, both-sides XOR swizzle. 3 blocks/CU at grid 768.
// ---------------------------------------------------------------------------
template <int EPI>
__global__ __launch_bounds__(512) void gemm_cv(
    const u16* __restrict__ A, const u16* __restrict__ Bt,
    const float* __restrict__ bias,
    u16* __restrict__ q_out, u16* __restrict__ k_out, u16* __restrict__ v_out,
    float* __restrict__ f_out, int M, int N, int K, int ntn)
{
    __shared__ __align__(16) u16 Al[2][128 * 32];
    __shared__ __align__(16) u16 Bl[2][128 * 32];
    const int tid = threadIdx.x, lane = tid & 63, w = tid >> 6;
    const int qd = gridDim.x >> 3;
    const int wg = (blockIdx.x & 7) * qd + (blockIdx.x >> 3);
    const int m0 = (wg / ntn) * 128, n0 = (wg % ntn) * 128;
    const int wm = w >> 2, wn = w & 3;

    f32x4 acc[4][2] = {};
    const int nt = K >> 5;

    const int srow = tid >> 2;
    const int skc  = ((tid & 3) ^ ((srow >> 1) & 3)) * 8;

#define STG(t_, s_) do {                                                       \
        const int kk_ = (t_) << 5;                                             \
        gl_lds(A + (size_t)(m0 + srow) * K + kk_ + skc,                        \
               (char*)&Al[s_][0] + w * 1024);                                  \
        gl_lds(Bt + (size_t)(n0 + srow) * K + kk_ + skc,                       \
               (char*)&Bl[s_][0] + w * 1024);                                  \
    } while (0)
#define BARX() do { __builtin_amdgcn_sched_barrier(0);                         \
        __builtin_amdgcn_s_barrier();                                          \
        __builtin_amdgcn_sched_barrier(0); } while (0)

    STG(0, 0);
    int buf = 0;
    for (int t = 0; t < nt; t++) {
        if (t + 1 < nt) {
            STG(t + 1, buf ^ 1);
            asm volatile("s_waitcnt vmcnt(2)" ::: "memory");
        } else {
            asm volatile("s_waitcnt vmcnt(0)" ::: "memory");
        }
        BARX();
        s8v af[4], bf[2];
        #pragma unroll
        for (int mi = 0; mi < 4; mi++) {
            const int row = wm * 64 + mi * 16 + (lane & 15);
            const int slot = (lane >> 4) ^ ((row >> 1) & 3);
            af[mi] = *(const s8v*)((const char*)&Al[buf][0] + row * 64 + slot * 16);
        }
        #pragma unroll
        for (int ni = 0; ni < 2; ni++) {
            const int row = wn * 32 + ni * 16 + (lane & 15);
            const int slot = (lane >> 4) ^ ((row >> 1) & 3);
            bf[ni] = *(const s8v*)((const char*)&Bl[buf][0] + row * 64 + slot * 16);
        }
        #pragma unroll
        for (int mi = 0; mi < 4; mi++)
            #pragma unroll
            for (int ni = 0; ni < 2; ni++)
                acc[mi][ni] = __builtin_amdgcn_mfma_f32_16x16x32_bf16(af[mi], bf[ni], acc[mi][ni], 0, 0, 0);
        BARX();
        buf ^= 1;
    }
#undef STG
#undef BARX

    #pragma unroll
    for (int mi = 0; mi < 4; mi++)
    #pragma unroll
    for (int ni = 0; ni < 2; ni++)
    #pragma unroll
    for (int r = 0; r < 4; r++) {
        const int row = m0 + wm * 64 + mi * 16 + (lane >> 4) * 4 + r;
        const int col = n0 + wn * 32 + ni * 16 + (lane & 15);
        const float val = acc[mi][ni][r] + bias[col];
        if constexpr (EPI == 0) {
            const int sel = col >> 10, rem = col & 1023;
            const int h = rem >> 6, d = rem & 63;
            const int b = row >> 11, tt = row & 2047;
            const size_t idx = ((size_t)(b * Hc + h) * Tc + tt) * DKc + d;
            if (sel == 0) q_out[idx] = f2b(val * QSCALE);
            else if (sel == 1) k_out[idx] = f2b(val);
            else v_out[idx] = f2b(val);
        } else {
            f_out[(size_t)row * N + col] = val;
        }
    }
}

// ---------------------------------------------------------------------------
// GEMM-N64: gemm_cv with BN=64 for GEMM2's narrow N. 128x64 tile, 512 thr,
// 8 waves as 4x2 of 32x32 (acc[2][2]). LDS 24KB -> grid 512 = 2 blocks/CU
// (16 waves/CU vs 8 at BN=128/grid 256). A staged by all threads (8KB);
// B (4KB) by waves 0-3 only -> per-wave counted vmcnt 2/1 (wave-uniform).
// ---------------------------------------------------------------------------
__global__ __launch_bounds__(512) void gemm_n64(
    const u16* __restrict__ A, const u16* __restrict__ Bt,
    const float* __restrict__ bias, float* __restrict__ f_out,
    int M, int N, int K, int ntn)
{
    __shared__ __align__(16) u16 Al[2][128 * 32];
    __shared__ __align__(16) u16 Bl[2][64 * 32];
    const int tid = threadIdx.x, lane = tid & 63, w = tid >> 6;
    const int qd = gridDim.x >> 3;
    const int wg = (blockIdx.x & 7) * qd + (blockIdx.x >> 3);
    const int m0 = (wg / ntn) * 128, n0 = (wg % ntn) * 64;
    const int wm = w >> 1, wn = w & 1;   // 4x2 wave grid of 32x32 tiles

    f32x4 acc[2][2] = {};
    const int nt = K >> 5;

    const int srow = tid >> 2;                           // A row 0..127
    const int skc  = ((tid & 3) ^ ((srow >> 1) & 3)) * 8;
    const int brow = (tid & 255) >> 2;                   // B row 0..63 (tid<256)
    const int bkc  = ((tid & 3) ^ ((brow >> 1) & 3)) * 8;

#define STG(t_, s_) do {                                                       \
        const int kk_ = (t_) << 5;                                             \
        gl_lds(A + (size_t)(m0 + srow) * K + kk_ + skc,                        \
               (char*)&Al[s_][0] + w * 1024);                                  \
        if (w < 4)                                                             \
            gl_lds(Bt + (size_t)(n0 + brow) * K + kk_ + bkc,                   \
                   (char*)&Bl[s_][0] + w * 1024);                              \
    } while (0)
#define BARX() do { __builtin_amdgcn_sched_barrier(0);                         \
        __builtin_amdgcn_s_barrier();                                          \
        __builtin_amdgcn_sched_barrier(0); } while (0)

    STG(0, 0);
    int buf = 0;
    for (int t = 0; t < nt; t++) {
        if (t + 1 < nt) {
            STG(t + 1, buf ^ 1);
            if (w < 4) { asm volatile("s_waitcnt vmcnt(2)" ::: "memory"); }
            else       { asm volatile("s_waitcnt vmcnt(1)" ::: "memory"); }
        } else {
            asm volatile("s_waitcnt vmcnt(0)" ::: "memory");
        }
        BARX();
        s8v af[2], bf[2];
        #pragma unroll
        for (int mi = 0; mi < 2; mi++) {
            const int row = wm * 32 + mi * 16 + (lane & 15);
            const int slot = (lane >> 4) ^ ((row >> 1) & 3);
            af[mi] = *(const s8v*)((const char*)&Al[buf][0] + row * 64 + slot * 16);
        }
        #pragma unroll
        for (int ni = 0; ni < 2; ni++) {
            const int row = wn * 32 + ni * 16 + (lane & 15);
            const int slot = (lane >> 4) ^ ((row >> 1) & 3);
            bf[ni] = *(const s8v*)((const char*)&Bl[buf][0] + row * 64 + slot * 16);
        }
        #pragma unroll
        for (int mi = 0; mi < 2; mi++)
            #pragma unroll
            for (int ni = 0; ni < 2; ni++)
                acc[mi][ni] = __builtin_amdgcn_mfma_f32_16x16x32_bf16(af[mi], bf[ni], acc[mi][ni], 0, 0, 0);
        BARX();
        buf ^= 1;
    }
#undef STG
#undef BARX

    #pragma unroll
    for (int mi = 0; mi < 2; mi++)
    #pragma unroll
    for (int ni = 0; ni < 2; ni++)
    #pragma unroll
    for (int r = 0; r < 4; r++) {
        const int row = m0 + wm * 32 + mi * 16 + (lane >> 4) * 4 + r;
        const int col = n0 + wn * 32 + ni * 16 + (lane & 15);
        f_out[(size_t)row * N + col] = acc[mi][ni][r] + bias[col];
    }
}

// ---------------------------------------------------------------------------
// Flash attention, causal, swapped-QK^T 32x32, m=0 linear accumulation.
// 512 threads = 2 wave-groups x 4 waves; group g owns k-half [g*h, g*h+h).
// ---------------------------------------------------------------------------
__global__ __launch_bounds__(512) void attn_fwd(
    const u16* __restrict__ Q, const u16* __restrict__ K,
    const u16* __restrict__ V, u16* __restrict__ O)
{
    __shared__ __align__(16) char Gl[2][2][2][8192];

    const int bid = blockIdx.x;
    const int bh = bid & 31;
    const int qt = 15 - (bid >> 5);
    const int tid = threadIdx.x;
    const int g = tid >> 8;
    const int gtid = tid & 255;
    const int lane = tid & 63;
    const int ws = (tid >> 6) & 3;
    const int hi = lane >> 5, lq = lane & 31;
    const int q0w = qt * 128 + ws * 32;
    const int qg = q0w + lq;

    const u16* Qb = Q + (size_t)bh * (Tc * DKc);
    const u16* Kb = K + (size_t)bh * (Tc * DKc);
    const u16* Vb = V + (size_t)bh * (Tc * DKc);

    s8v qf[4];
    #pragma unroll
    for (int st = 0; st < 4; st++)
        qf[st] = *(const s8v*)(Qb + (size_t)qg * 64 + st * 16 + hi * 8);

    f32x16 o0 = {}, o1 = {}, lacc = {};

    const int dtw = (q0w + 31) >> 6;
    const int h = qt + 1;
    const int t0 = g * h;

    char* const Kbase = &Gl[g][0][0][0];
    char* const Vbase = &Gl[g][1][0][0];

    const int d2 = (gtid & 31) * 2, kb8 = gtid >> 5;
    const unsigned vsw0 = ((unsigned)(d2 & 7)) << 4;
    const unsigned vsw1 = ((unsigned)((d2 + 1) & 7)) << 4;
    const unsigned ksw = ((unsigned)(lq & 7)) << 4;

    u32 vx[8];

#define ISSUE_K(kt_, dst_) do {                                              \
        const char* Ktile_ = (const char*)(Kb + (size_t)(kt_) * 4096);       \
        _Pragma("unroll")                                                    \
        for (int s_ = 0; s_ < 2; s_++) {                                     \
            const int o_ = s_ * 4096 + gtid * 16;                            \
            const int rk_ = o_ >> 7;                                         \
            const int cb_ = (o_ & 127) ^ ((rk_ & 7) << 4);                   \
            gl_lds(Ktile_ + rk_ * 128 + cb_, (dst_) + s_ * 4096 + ws * 1024); \
        }                                                                    \
    } while (0)

#define LOAD_V(kt_) do {                                                     \
        const u16* Vtile_ = Vb + (size_t)(kt_) * 4096;                       \
        _Pragma("unroll")                                                    \
        for (int i_ = 0; i_ < 8; i_++)                                       \
            vx[i_] = *(const u32*)(Vtile_ + (kb8 * 8 + i_) * 64 + d2);       \
    } while (0)

#define WRITE_V(dst_) do {                                                   \
        s8v v0_, v1_;                                                        \
        _Pragma("unroll")                                                    \
        for (int i_ = 0; i_ < 8; i_++) {                                     \
            v0_[i_] = (short)(vx[i_] & 0xffff);                              \
            v1_[i_] = (short)(vx[i_] >> 16);                                 \
        }                                                                    \
        *(s8v*)((dst_) + d2 * 128 + (((unsigned)(kb8 * 16)) ^ vsw0)) = v0_;  \
        *(s8v*)((dst_) + (d2 + 1) * 128 + (((unsigned)(kb8 * 16)) ^ vsw1)) = v1_; \
    } while (0)

    ISSUE_K(t0, Kbase);
    LOAD_V(t0);
    WRITE_V(Vbase);
    __syncthreads();

    int c = 0;
    for (int i = 0; i < h; i++) {
        const int tki = t0 + i;
        const bool pf_next = (i + 1 < h);
        if (pf_next) {
            ISSUE_K(tki + 1, Kbase + (c ^ 1) * 8192);
            LOAD_V(tki + 1);
        }

        if (tki <= dtw) {
            const char* Kc = Kbase + c * 8192;
            const char* Vc = Vbase + c * 8192;
            f32x16 s0v = {}, s1v = {};
            __builtin_amdgcn_s_setprio(1);
            #pragma unroll
            for (int st = 0; st < 4; st++) {
                const unsigned cbs = (unsigned)(st * 32 + hi * 16);
                s8v kf0 = *(const s8v*)(Kc + lq * 128 + (cbs ^ ksw));
                s8v kf1 = *(const s8v*)(Kc + (32 + lq) * 128 + (cbs ^ ksw));
                s0v = __builtin_amdgcn_mfma_f32_32x32x16_bf16(kf0, qf[st], s0v, 0, 0, 0);
                s1v = __builtin_amdgcn_mfma_f32_32x32x16_bf16(kf1, qf[st], s1v, 0, 0, 0);
            }
            __builtin_amdgcn_s_setprio(0);

            if (tki == dtw) {
                #pragma unroll
                for (int r = 0; r < 16; r++) {
                    const int kg = tki * 64 + (r & 3) + 8 * (r >> 2) + 4 * hi;
                    if (kg > qg) s0v[r] = -INFINITY;
                    if (kg + 32 > qg) s1v[r] = -INFINITY;
                }
            }

            #pragma unroll
            for (int r = 0; r < 16; r++) {
                s0v[r] = vexp2(s0v[r]);
                s1v[r] = vexp2(s1v[r]);
            }
            lacc += s0v;
            lacc += s1v;

            i32x4 pf[4];
            #pragma unroll
            for (int gq = 0; gq < 2; gq++) {
                #pragma unroll
                for (int hq = 0; hq < 2; hq++) {
                    const int base = hq * 8;
                    u32 a0, a1, b0, b1;
                    if (gq == 0) {
                        a0 = pkbf16(s0v[base + 0], s0v[base + 1]);
                        a1 = pkbf16(s0v[base + 2], s0v[base + 3]);
                        b0 = pkbf16(s0v[base + 4], s0v[base + 5]);
                        b1 = pkbf16(s0v[base + 6], s0v[base + 7]);
                    } else {
                        a0 = pkbf16(s1v[base + 0], s1v[base + 1]);
                        a1 = pkbf16(s1v[base + 2], s1v[base + 3]);
                        b0 = pkbf16(s1v[base + 4], s1v[base + 5]);
                        b1 = pkbf16(s1v[base + 6], s1v[base + 7]);
                    }
                    pl32swap(a0, b0);
                    pl32swap(a1, b1);
                    pf[gq * 2 + hq][0] = (int)a0;
                    pf[gq * 2 + hq][1] = (int)a1;
                    pf[gq * 2 + hq][2] = (int)b0;
                    pf[gq * 2 + hq][3] = (int)b1;
                }
            }

            __builtin_amdgcn_s_setprio(1);
            #pragma unroll
            for (int ks = 0; ks < 4; ks++) {
                const unsigned cbv = (unsigned)(ks * 32 + hi * 16);
                s8v vf0 = *(const s8v*)(Vc + lq * 128 + (cbv ^ ksw));
                s8v vf1 = *(const s8v*)(Vc + (32 + lq) * 128 + (cbv ^ ksw));
                const s8v pa = as_s8v(pf[ks]);
                o0 = __builtin_amdgcn_mfma_f32_32x32x16_bf16(pa, vf0, o0, 0, 0, 0);
                o1 = __builtin_amdgcn_mfma_f32_32x32x16_bf16(pa, vf1, o1, 0, 0, 0);
            }
            __builtin_amdgcn_s_setprio(0);
        }

        if (pf_next) WRITE_V(Vbase + (c ^ 1) * 8192);
        __syncthreads();
        c ^= 1;
    }

    float t8[8];
    #pragma unroll
    for (int r = 0; r < 8; r++) t8[r] = lacc[r] + lacc[r + 8];
    #pragma unroll
    for (int off = 4; off >= 1; off >>= 1)
        #pragma unroll
        for (int r = 0; r < off; r++) t8[r] = t8[r] + t8[r + off];
    float ls = t8[0] + __shfl_xor(t8[0], 32);

    float* Pf = (float*)(&Gl[0][0][0][0]) + ws * 2304;
    if (g == 1) {
        float* dst = Pf + lane * 34;
        #pragma unroll
        for (int r = 0; r < 16; r++) { dst[r] = o0[r]; dst[16 + r] = o1[r]; }
        Pf[2176 + lane] = ls;
    }
    __syncthreads();
    if (g == 0) {
        const float* src = Pf + lane * 34;
        #pragma unroll
        for (int r = 0; r < 16; r++) { o0[r] += src[r]; o1[r] += src[16 + r]; }
        ls += Pf[2176 + lane];

        const float linv = 1.0f / ls;
        const int b = bh >> 4, hh = bh & 15;
        u16* Ob = O + ((size_t)b * Tc) * DMc + hh * 64;
        #pragma unroll
        for (int r = 0; r < 16; r++) {
            const int cr = (r & 3) + 8 * (r >> 2) + 4 * hi;
            const float ir = __shfl(linv, cr);
            u16* orow = Ob + (size_t)(q0w + cr) * DMc;
            orow[lq]      = f2b(o0[r] * ir);
            orow[32 + lq] = f2b(o1[r] * ir);
        }
    }
#undef ISSUE_K
#undef LOAD_V
#undef WRITE_V
}

// ---------------------------------------------------------------------------
extern "C" void kernel_launch(void* const* d_in, const int* in_sizes, int n_in,
                              void* d_out, int out_size, void* d_ws, size_t ws_size,
                              hipStream_t stream)
{
    const float* X    = (const float*)d_in[0];
    const float* Wqkv = (const float*)d_in[1];
    const float* bqkv = (const float*)d_in[2];
    const float* Wout = (const float*)d_in[3];
    const float* bout = (const float*)d_in[4];
    float* out = (float*)d_out;

    char* ws = (char*)d_ws;
    u16* Xb  = (u16*)(ws);                      // 8 MB (dead after GEMM1)
    u16* Ow  = (u16*)(ws);                      // 8 MB (overlays Xb)
    u16* Wt1 = (u16*)(ws + (8 << 20));          // 6 MB
    u16* Wt2 = (u16*)(ws + (14 << 20));         // 2 MB
    u16* Qw  = (u16*)(ws + (16 << 20));         // 8 MB
    u16* Kw  = (u16*)(ws + (24 << 20));         // 8 MB
    u16* Vw  = (u16*)(ws + (32 << 20));         // 8 MB

    // fused prepass: conv(1024) + transw Wqkv(768) + transw Wout(256)
    prepass<<<2048, 256, 0, stream>>>(X, Xb, Wqkv, Wt1, Wout, Wt2);

    // GEMM1: champion gemm_cv, grid 768 (3 blocks/CU)
    gemm_cv<0><<<768, 512, 0, stream>>>(
        Xb, Wt1, bqkv, Qw, Kw, Vw, nullptr, Bc * Tc, NQKV, DMc, NQKV / 128);

    attn_fwd<<<512, 512, 0, stream>>>(Qw, Kw, Vw, Ow);

    // GEMM2: BN=64 variant, grid 32*16 = 512 (2 blocks/CU, 16 waves/CU)
    gemm_n64<<<512, 512, 0, stream>>>(
        Ow, Wt2, bout, out, Bc * Tc, DMc, DMc, DMc / 64);
}